// Round 14
// baseline (1165.737 us; speedup 1.0000x reference)
//
#include <hip/hip_runtime.h>
#include <hip/hip_bf16.h>
#include <hip/hip_fp16.h>
#include <math.h>

// Problem constants
#define B_   64
#define SWP  512
#define D_   768
#define W_   256     // NUM_WORDS
#define H_   256
#define G4   1024    // 4*H
#define N2   2048    // both dirs' gates
#define M_   16384   // B_*W_ rows
#define A_   8
#define KK_  4

typedef __attribute__((ext_vector_type(4))) float f32x4;
typedef __attribute__((ext_vector_type(2))) float f32x2;
typedef __attribute__((ext_vector_type(8))) short bf16x8;
typedef __attribute__((ext_vector_type(4))) unsigned u32x4;
typedef _Float16 __attribute__((ext_vector_type(2))) h2_t;

// k_lstm v13: fully-resident fp8 (R13) + stall fixes:
//   - rows remapped so thread 2u = (i,f), 2u+1 = (g,o) of unit u
//     -> gate exchange by 2x ds_swizzle (same wave), fo buffer deleted
//   - single barrier/step with double-buffered hbuf
//   - LDS weight reads software-pipelined 2 chunks ahead (static staging)
#define NVD 28   // VGPR dwords per row (2 pairs each): pairs 0..55
#define NLC 18   // LDS u32x4 chunks per thread (9 per row): pairs 56..127

__device__ __forceinline__ void gload_lds16(const void* g, void* l) {
  __builtin_amdgcn_global_load_lds((const __attribute__((address_space(1))) void*)g,
                                   (__attribute__((address_space(3))) void*)l, 16, 0, 0);
}

__device__ __forceinline__ float sigm(float x) { return 1.f / (1.f + __expf(-x)); }
__device__ __forceinline__ float tanh_(float x) { return 1.f - 2.f / (1.f + __expf(2.f * x)); }

__device__ __forceinline__ float dot2acc(h2_t w, h2_t h, float acc) {
#if __has_builtin(__builtin_amdgcn_fdot2)
  return __builtin_amdgcn_fdot2(w, h, acc, false);
#else
  return acc + (float)w[0] * (float)h[0] + (float)w[1] * (float)h[1];
#endif
}

__device__ __forceinline__ h2_t bc_h2(unsigned int v) {
  union { unsigned u; h2_t h; } c; c.u = v; return c.h;
}

__device__ __forceinline__ h2_t pk16(float a, float b) {
  auto v = __builtin_amdgcn_cvt_pkrtz(a, b);
  union { decltype(v) x; h2_t h; } u; u.x = v; return u.h;
}

// decode one fp8 pair (low/high word of dw) to f16 pair. HI compile-time (R12).
template <bool HI>
__device__ __forceinline__ h2_t dec8(unsigned dw) {
  f32x2 f = __builtin_amdgcn_cvt_pk_f32_fp8((int)dw, HI);
  return pk16(f[0], f[1]);
}

// software f32 -> OCP e4m3fn encoder (prep-time only; R11-proven)
__device__ unsigned enc_e4m3(float x) {
  if (x != x) return 0x7f;
  unsigned s = 0; if (x < 0.f) { s = 0x80; x = -x; }
  if (x >= 448.f) return s | 0x7e;
  if (x < 0.0009765625f) return s;
  int e; float m = frexpf(x, &e);
  int E = e + 6;
  if (E >= 1) {
    unsigned mant = (unsigned)rintf(m * 16.f - 8.f);
    if (mant == 8) { mant = 0; ++E; }
    if (E > 15 || (E == 15 && mant == 7)) return s | 0x7e;
    return s | ((unsigned)E << 3) | mant;
  } else {
    unsigned dm = (unsigned)rintf(x * 512.f);
    if (dm >= 8) return s | 0x08;
    return s | dm;
  }
}

// Row mapping (prep + lstm must agree): thread t -> unit u=t>>1, o=t&1.
//   o=0: rows i(u), f(256+u).  o=1: rows g(512+u), o(768+u).
__device__ __forceinline__ int row1_of(int t) { return (t >> 1) + ((t & 1) ? 512 : 0); }
__device__ __forceinline__ int row2_of(int t) { return (t >> 1) + ((t & 1) ? 768 : 256); }

// K1: scatter-mean wordpieces -> words (bf16). One block per (b, word).
__global__ __launch_bounds__(256) void k_words(const float* __restrict__ emb,
                                               const int* __restrict__ mask,
                                               __hip_bfloat16* __restrict__ words) {
  const int b = blockIdx.x >> 8;
  const int w = blockIdx.x & 255;
  const int tid = threadIdx.x;
  __shared__ int m[SWP];
  m[tid] = mask[b * SWP + tid];
  m[tid + 256] = mask[b * SWP + 256 + tid];
  __syncthreads();
  int lo = 0, hi = SWP;
  while (lo < hi) { int mid = (lo + hi) >> 1; if (m[mid] < w) lo = mid + 1; else hi = mid; }
  int lo2 = lo, hi2 = SWP;
  while (lo2 < hi2) { int mid = (lo2 + hi2) >> 1; if (m[mid] < w + 1) lo2 = mid + 1; else hi2 = mid; }
  const int cnt = lo2 - lo;
  const float inv = (cnt > 0) ? 1.f / (float)cnt : 0.f;
  float s0 = 0.f, s1 = 0.f, s2 = 0.f;
  for (int s = lo; s < lo2; ++s) {
    const float* row = emb + ((size_t)b * SWP + s) * D_;
    s0 += row[tid]; s1 += row[tid + 256]; s2 += row[tid + 512];
  }
  __hip_bfloat16* o = words + ((size_t)b * W_ + w) * D_;
  o[tid]       = __float2bfloat16(s0 * inv);
  o[tid + 256] = __float2bfloat16(s1 * inv);
  o[tid + 512] = __float2bfloat16(s2 * inv);
}

// K2a: concat+convert input weights to bf16 [2048][768]; fused bias [2048]
__global__ __launch_bounds__(256) void k_prep_wih(const float* __restrict__ wf, const float* __restrict__ wr,
                                                  const float* __restrict__ bihf, const float* __restrict__ bhhf,
                                                  const float* __restrict__ bihr, const float* __restrict__ bhhr,
                                                  __hip_bfloat16* __restrict__ wih, float* __restrict__ bias) {
  const int i = blockIdx.x * 256 + threadIdx.x;
  const int n = i / D_;
  const int k = i - n * D_;
  const float v = (n < G4) ? wf[n * D_ + k] : wr[(n - G4) * D_ + k];
  wih[i] = __float2bfloat16(v);
  if (i < N2) {
    bias[i] = (i < G4) ? (bihf[i] + bhhf[i]) : (bihr[i - G4] + bhhr[i - G4]);
  }
}

// K2b: repack w_hh as half2 [dir][128 kk][1024 r]
__global__ __launch_bounds__(256) void k_prep_whh(const float* __restrict__ whf,
                                                  const float* __restrict__ whr,
                                                  h2_t* __restrict__ whhP) {
  const int i = blockIdx.x * 256 + threadIdx.x;   // 2*128*1024
  const int d = i >> 17;
  const int kk = (i >> 10) & 127;
  const int r = i & 1023;
  const float* w = d ? whr : whf;
  h2_t v;
  v[0] = (_Float16)w[r * H_ + 2 * kk];
  v[1] = (_Float16)w[r * H_ + 2 * kk + 1];
  whhP[i] = v;
}

// K2c: VGPR-tier fp8 pack. wv8[d][c][t]: c<28 -> row1(t), c>=28 -> row2(t);
// dword = pairs (2*(c%28), 2*(c%28)+1)
__global__ __launch_bounds__(256) void k_prep_wv8(const h2_t* __restrict__ whhP,
                                                  unsigned* __restrict__ wv8) {
  const int i = blockIdx.x * 256 + threadIdx.x;   // 2*56*512
  if (i >= 2 * 2 * NVD * 512) return;
  const int t = i & 511;
  const int c = (i >> 9) % (2 * NVD);
  const int d = i / (2 * NVD * 512);
  const int row = (c < NVD) ? row1_of(t) : row2_of(t);
  const int pb = 2 * (c % NVD);
  const h2_t* wp = whhP + (size_t)d * (128 * 1024);
  const h2_t p0 = wp[pb * 1024 + row];
  const h2_t p1 = wp[(pb + 1) * 1024 + row];
  wv8[i] = enc_e4m3((float)p0[0]) | (enc_e4m3((float)p0[1]) << 8)
         | (enc_e4m3((float)p1[0]) << 16) | (enc_e4m3((float)p1[1]) << 24);
}

// K2d: LDS-tier fp8 pack. wl8[d][c][t] (u32x4): c<9 -> row1, c>=9 -> row2;
// dword q: pairs (ps+2q, ps+2q+1), ps = 56 + 8*(c%9)
__global__ __launch_bounds__(256) void k_prep_wl8(const h2_t* __restrict__ whhP,
                                                  u32x4* __restrict__ wl8) {
  const int i = blockIdx.x * 256 + threadIdx.x;   // 2*18*512
  if (i >= 2 * NLC * 512) return;
  const int t = i & 511;
  const int c = (i >> 9) % NLC;
  const int d = i / (NLC * 512);
  const int row = (c < 9) ? row1_of(t) : row2_of(t);
  const int ps = 56 + 8 * (c % 9);
  const h2_t* wp = whhP + (size_t)d * (128 * 1024);
  u32x4 v;
#pragma unroll
  for (int q = 0; q < 4; ++q) {
    const h2_t p0 = wp[(ps + 2 * q) * 1024 + row];
    const h2_t p1 = wp[(ps + 2 * q + 1) * 1024 + row];
    v[q] = enc_e4m3((float)p0[0]) | (enc_e4m3((float)p0[1]) << 8)
         | (enc_e4m3((float)p1[0]) << 16) | (enc_e4m3((float)p1[1]) << 24);
  }
  wl8[i] = v;
}

// K3: xg = words @ W_ih^T + bias, bf16 MFMA, 128x128 tile, out f16
__global__ __launch_bounds__(256) void k_gemm_xg(const __hip_bfloat16* __restrict__ A,
                                                 const __hip_bfloat16* __restrict__ Wt,
                                                 const float* __restrict__ bias,
                                                 _Float16* __restrict__ C) {
  const int bm = blockIdx.y * 128;
  const int bn = blockIdx.x * 128;
  __shared__ __hip_bfloat16 As[128 * 32];
  __shared__ __hip_bfloat16 Bs[128 * 32];
  const int tid = threadIdx.x;
  const int lane = tid & 63;
  const int wave = tid >> 6;
  const int wm = (wave >> 1) * 64;
  const int wn = (wave & 1) * 64;
  const int l15 = lane & 15;
  const int l4 = lane >> 4;
  const int row_a = tid >> 2;
  const int chunk = tid & 3;
  f32x4 acc[4][4] = {};
  for (int k0 = 0; k0 < D_; k0 += 32) {
    const __hip_bfloat16* ga  = A  + (size_t)(bm + row_a) * D_ + k0 + chunk * 8;
    const __hip_bfloat16* ga2 = A  + (size_t)(bm + 64 + row_a) * D_ + k0 + chunk * 8;
    const __hip_bfloat16* gb  = Wt + (size_t)(bn + row_a) * D_ + k0 + chunk * 8;
    const __hip_bfloat16* gb2 = Wt + (size_t)(bn + 64 + row_a) * D_ + k0 + chunk * 8;
    gload_lds16(ga,  As + tid * 8);
    gload_lds16(ga2, As + 2048 + tid * 8);
    gload_lds16(gb,  Bs + tid * 8);
    gload_lds16(gb2, Bs + 2048 + tid * 8);
    __syncthreads();
    bf16x8 af[4], bf[4];
#pragma unroll
    for (int i = 0; i < 4; ++i) {
      af[i] = *(const bf16x8*)(As + (wm + i * 16 + l15) * 32 + l4 * 8);
      bf[i] = *(const bf16x8*)(Bs + (wn + i * 16 + l15) * 32 + l4 * 8);
    }
#pragma unroll
    for (int i = 0; i < 4; ++i)
#pragma unroll
      for (int j = 0; j < 4; ++j)
        acc[i][j] = __builtin_amdgcn_mfma_f32_16x16x32_bf16(af[i], bf[j], acc[i][j], 0, 0, 0);
    __syncthreads();
  }
#pragma unroll
  for (int i = 0; i < 4; ++i) {
    const int m = bm + wm + i * 16 + l4 * 4;
#pragma unroll
    for (int j = 0; j < 4; ++j) {
      const int n = bn + wn + j * 16 + l15;
      const float bs = bias[n];
#pragma unroll
      for (int r = 0; r < 4; ++r)
        C[(size_t)(m + r) * N2 + n] = (_Float16)(acc[i][j][r] + bs);
    }
  }
}

// one 8-pair LDS chunk (pairs PS..PS+7) for both rows from staged u32x4
template <int PS>
__device__ __forceinline__ void lds_chunk(const u32x4& w1, const u32x4& w2,
                                          unsigned hA, unsigned hB,
                                          float& a1a, float& a1b,
                                          float& a2a, float& a2b) {
#pragma unroll
  for (int q = 0; q < 4; ++q) {
    const int p = PS + 2 * q;
    const h2_t h0 = bc_h2((p < 64) ? __builtin_amdgcn_readlane(hA, p)
                                   : __builtin_amdgcn_readlane(hB, p - 64));
    const h2_t h1 = bc_h2((p + 1 < 64) ? __builtin_amdgcn_readlane(hA, p + 1)
                                       : __builtin_amdgcn_readlane(hB, p - 63));
    a1a = dot2acc(dec8<false>(w1[q]), h0, a1a);
    a1b = dot2acc(dec8<true >(w1[q]), h1, a1b);
    a2a = dot2acc(dec8<false>(w2[q]), h0, a2a);
    a2b = dot2acc(dec8<true >(w2[q]), h1, a2b);
  }
}

// K4 v13: fully-resident fp8, swizzle gate exchange, 1 barrier/step,
// pipelined LDS weight reads. Block = (dir, batch), 512 threads.
__global__ __launch_bounds__(512)
void k_lstm(const _Float16* __restrict__ xg,     // [M_][2048]
            const unsigned* __restrict__ wv8,    // [2][56][512]
            const u32x4* __restrict__ wl8,       // [2][18][512]
            float* __restrict__ out) {           // [B_][W_][512]
  const int bx = blockIdx.x;
  const int d = bx & 1;
  const int b = bx >> 1;
  const int t = threadIdx.x;
  const int u = t >> 1;
  const int o = t & 1;
  const int l = t & 63;
  const int r1 = row1_of(t);
  const int r2 = row2_of(t);

  __shared__ __align__(16) _Float16 hbuf[2][256];
  __shared__ __align__(16) u32x4 wlds[NLC][512];   // 144 KB fp8: pairs 56..127

  // VGPR tier: 56 fp8-packed dwords (pairs 0..55 of both rows)
  unsigned wv[2 * NVD];
  {
    const unsigned* src = wv8 + (size_t)d * (2 * NVD * 512);
#pragma unroll
    for (int c = 0; c < 2 * NVD; ++c) wv[c] = src[c * 512 + t];
  }
  // LDS tier: stage 18 x 16B per thread (pairs 56..127 of both rows)
  {
    const u32x4* src = wl8 + (size_t)d * (NLC * 512);
#pragma unroll
    for (int c = 0; c < NLC; ++c) wlds[c][t] = src[c * 512 + t];
  }
  if (t < 256) hbuf[0][t] = (_Float16)0.f;
  __syncthreads();

  float c_state = 0.f;
#pragma unroll 1
  for (int step = 0; step < W_; ++step) {
    const int cur = step & 1;
    const int tt = d ? (W_ - 1 - step) : step;
    const _Float16* xrow = xg + ((size_t)b * W_ + tt) * N2 + d * G4;
    const _Float16 xr1 = xrow[r1];   // issue early, convert late
    const _Float16 xr2 = xrow[r2];
    float a1a = 0.f, a1b = 0.f, a2a = 0.f, a2b = 0.f;
    if (step > 0) {
      const unsigned hA = *(const unsigned*)&hbuf[cur][2 * l];
      const unsigned hB = *(const unsigned*)&hbuf[cur][128 + 2 * l];
      // prefetch LDS chunks 0,1 before the register-tier compute
      u32x4 sA1 = wlds[0][t], sA2 = wlds[9][t];
      u32x4 sB1 = wlds[1][t], sB2 = wlds[10][t];
      // ---- VGPR tier: pairs 0..55 (covers LDS latency) ----
#pragma unroll
      for (int c = 0; c < NVD; ++c) {
        const h2_t h0 = bc_h2(__builtin_amdgcn_readlane(hA, 2 * c));
        const h2_t h1 = bc_h2(__builtin_amdgcn_readlane(hA, 2 * c + 1));
        a1a = dot2acc(dec8<false>(wv[c]), h0, a1a);
        a1b = dot2acc(dec8<true >(wv[c]), h1, a1b);
        a2a = dot2acc(dec8<false>(wv[NVD + c]), h0, a2a);
        a2b = dot2acc(dec8<true >(wv[NVD + c]), h1, a2b);
      }
      // ---- LDS tier: pairs 56..127, 2-chunk-ahead rotation ----
      lds_chunk<56>(sA1, sA2, hA, hB, a1a, a1b, a2a, a2b);
      sA1 = wlds[2][t]; sA2 = wlds[11][t];
      lds_chunk<64>(sB1, sB2, hA, hB, a1a, a1b, a2a, a2b);
      sB1 = wlds[3][t]; sB2 = wlds[12][t];
      lds_chunk<72>(sA1, sA2, hA, hB, a1a, a1b, a2a, a2b);
      sA1 = wlds[4][t]; sA2 = wlds[13][t];
      lds_chunk<80>(sB1, sB2, hA, hB, a1a, a1b, a2a, a2b);
      sB1 = wlds[5][t]; sB2 = wlds[14][t];
      lds_chunk<88>(sA1, sA2, hA, hB, a1a, a1b, a2a, a2b);
      sA1 = wlds[6][t]; sA2 = wlds[15][t];
      lds_chunk<96>(sB1, sB2, hA, hB, a1a, a1b, a2a, a2b);
      sB1 = wlds[7][t]; sB2 = wlds[16][t];
      lds_chunk<104>(sA1, sA2, hA, hB, a1a, a1b, a2a, a2b);
      sA1 = wlds[8][t]; sA2 = wlds[17][t];
      lds_chunk<112>(sB1, sB2, hA, hB, a1a, a1b, a2a, a2b);
      lds_chunk<120>(sA1, sA2, hA, hB, a1a, a1b, a2a, a2b);
    }
    const float a1 = a1a + a1b + (float)xr1;
    const float a2 = a2a + a2b + (float)xr2;
    // exchange with partner lane (t^1, same wave) — no barrier
    const float p1 = __uint_as_float(
        (unsigned)__builtin_amdgcn_ds_swizzle((int)__float_as_uint(a1), 0x041F));
    const float p2 = __uint_as_float(
        (unsigned)__builtin_amdgcn_ds_swizzle((int)__float_as_uint(a2), 0x041F));
    // o=0 thread has (i,f)=(a1,a2), partner's (g,o)=(p1,p2); o=1 mirrored.
    const float ig = sigm(o ? p1 : a1);
    const float fg = sigm(o ? p2 : a2);
    const float gg = tanh_(o ? a1 : p1);
    const float og = sigm(o ? a2 : p2);
    c_state = fg * c_state + ig * gg;
    const float h = og * tanh_(c_state);
    if (!o) {
      out[((size_t)b * W_ + tt) * 512 + d * 256 + u] = h;
      hbuf[cur ^ 1][u] = (_Float16)h;
    }
    __syncthreads();   // single barrier: hbuf[next] ready
  }
}

// K5: sent-mean + aspect gather-mean + fc1(relu) + fc2. One block per batch.
__global__ __launch_bounds__(256) void k_head(const float* __restrict__ out,
                                              const int* __restrict__ aidx,
                                              const float* __restrict__ fc1w,
                                              const float* __restrict__ fc1b,
                                              const float* __restrict__ fc2w,
                                              const float* __restrict__ fc2b,
                                              float* __restrict__ logits) {
  const int b = blockIdx.x;
  const int t = threadIdx.x;
  __shared__ float emb[A_][1024];
  __shared__ float h1[A_][256];
  __shared__ float sent[512];
  const float* ob = out + (size_t)b * W_ * 512;
  float s0 = 0.f, s1 = 0.f;
  for (int tt = 0; tt < W_; ++tt) {
    s0 += ob[tt * 512 + t];
    s1 += ob[tt * 512 + 256 + t];
  }
  sent[t] = s0 * (1.f / 256.f);
  sent[t + 256] = s1 * (1.f / 256.f);
  __syncthreads();
  for (int a = 0; a < A_; ++a) {
    int nv = 0;
    float m0 = 0.f, m1 = 0.f;
    for (int k = 0; k < KK_; ++k) {
      const int idx = aidx[(b * A_ + a) * KK_ + k];
      if (idx >= 0) {
        const int tt = min(idx, W_ - 2) + 1;
        m0 += ob[tt * 512 + t];
        m1 += ob[tt * 512 + 256 + t];
        nv++;
      }
    }
    const float inv = nv > 0 ? 1.f / (float)nv : 0.f;
    const bool valid = nv > 0;
    emb[a][t]        = valid ? sent[t] : 0.f;
    emb[a][t + 256]  = valid ? sent[t + 256] : 0.f;
    emb[a][512 + t]       = m0 * inv;
    emb[a][512 + 256 + t] = m1 * inv;
  }
  __syncthreads();
  {
    float acc[A_];
#pragma unroll
    for (int a = 0; a < A_; ++a) acc[a] = fc1b[t];
    const float* wrow = fc1w + (size_t)t * 1024;
    for (int j = 0; j < 1024; j += 4) {
      const float4 w = *(const float4*)(wrow + j);
#pragma unroll
      for (int a = 0; a < A_; ++a) {
        const float4 e = *(const float4*)(&emb[a][j]);
        acc[a] += w.x * e.x + w.y * e.y + w.z * e.z + w.w * e.w;
      }
    }
#pragma unroll
    for (int a = 0; a < A_; ++a) h1[a][t] = fmaxf(acc[a], 0.f);
  }
  __syncthreads();
  if (t < A_ * 4) {
    const int a = t >> 2, l = t & 3;
    float acc = fc2b[l];
    const float* w = fc2w + l * 256;
    for (int j = 0; j < 256; ++j) acc += w[j] * h1[a][j];
    logits[(b * A_ + a) * 4 + l] = acc;
  }
}

extern "C" void kernel_launch(void* const* d_in, const int* in_sizes, int n_in,
                              void* d_out, int out_size, void* d_ws, size_t ws_size,
                              hipStream_t stream) {
  const float* emb  = (const float*)d_in[0];
  const int*   mask = (const int*)d_in[1];
  const int*   aidx = (const int*)d_in[2];
  const float* wihf = (const float*)d_in[3];
  const float* whhf = (const float*)d_in[4];
  const float* bihf = (const float*)d_in[5];
  const float* bhhf = (const float*)d_in[6];
  const float* wihr = (const float*)d_in[7];
  const float* whhr = (const float*)d_in[8];
  const float* bihr = (const float*)d_in[9];
  const float* bhhr = (const float*)d_in[10];
  const float* fc1w = (const float*)d_in[11];
  const float* fc1b = (const float*)d_in[12];
  const float* fc2w = (const float*)d_in[13];
  const float* fc2b = (const float*)d_in[14];
  float* logits = (float*)d_out;

  char* ws = (char*)d_ws;
  size_t off = 0;
  auto alloc = [&](size_t bytes) -> void* {
    void* p = ws + off;
    off += (bytes + 255) & ~(size_t)255;
    return p;
  };
  __hip_bfloat16* words = (__hip_bfloat16*)alloc((size_t)M_ * D_ * 2);
  _Float16*       xg    = (_Float16*)alloc((size_t)M_ * N2 * 2);
  __hip_bfloat16* wih   = (__hip_bfloat16*)alloc((size_t)N2 * D_ * 2);
  float*          bias  = (float*)alloc((size_t)N2 * 4);
  h2_t*           whhP  = (h2_t*)alloc((size_t)2 * 128 * 1024 * 4);
  unsigned*       wv8   = (unsigned*)alloc((size_t)2 * 2 * NVD * 512 * 4);
  u32x4*          wl8   = (u32x4*)alloc((size_t)2 * NLC * 512 * 16);
  float*          outh  = (float*)alloc((size_t)B_ * W_ * 512 * 4);

  k_words<<<B_ * W_, 256, 0, stream>>>(emb, mask, words);
  k_prep_wih<<<(N2 * D_) / 256, 256, 0, stream>>>(wihf, wihr, bihf, bhhf, bihr, bhhr, wih, bias);
  k_prep_whh<<<(2 * 128 * 1024) / 256, 256, 0, stream>>>(whhf, whhr, whhP);
  k_prep_wv8<<<(2 * 2 * NVD * 512 + 255) / 256, 256, 0, stream>>>(whhP, wv8);
  k_prep_wl8<<<(2 * NLC * 512 + 255) / 256, 256, 0, stream>>>(whhP, wl8);
  dim3 gg(N2 / 128, M_ / 128);
  k_gemm_xg<<<gg, 256, 0, stream>>>(words, wih, bias, xg);
  k_lstm<<<B_ * 2, 512, 0, stream>>>(xg, wv8, wl8, outh);
  k_head<<<B_, 256, 0, stream>>>(outh, aidx, fc1w, fc1b, fc2w, fc2b, logits);
}

// Round 15
// 659.602 us; speedup vs baseline: 1.7673x; 1.7673x over previous
//
#include <hip/hip_runtime.h>
#include <hip/hip_bf16.h>
#include <hip/hip_fp16.h>

// Problem constants
#define B_   64
#define SWP  512
#define D_   768
#define W_   256     // NUM_WORDS
#define H_   256
#define G4   1024    // 4*H
#define N2   2048    // both dirs' gates
#define M_   16384   // B_*W_ rows
#define A_   8
#define KK_  4

typedef __attribute__((ext_vector_type(4))) float f32x4;
typedef __attribute__((ext_vector_type(8))) short bf16x8;
typedef _Float16 __attribute__((ext_vector_type(2))) h2_t;

#define KR2 100  // h2 k-pairs per gate row pinned in VGPRs (pairs 0..99)
#define NCH 14   // LDS weight chunks: 7 per row x 2 rows (pairs 100..127)

__device__ __forceinline__ void gload_lds16(const void* g, void* l) {
  __builtin_amdgcn_global_load_lds((const __attribute__((address_space(1))) void*)g,
                                   (__attribute__((address_space(3))) void*)l, 16, 0, 0);
}

__device__ __forceinline__ float sigm(float x) { return 1.f / (1.f + __expf(-x)); }
__device__ __forceinline__ float tanh_(float x) { return 1.f - 2.f / (1.f + __expf(2.f * x)); }

__device__ __forceinline__ float dot2acc(h2_t w, h2_t h, float acc) {
#if __has_builtin(__builtin_amdgcn_fdot2)
  return __builtin_amdgcn_fdot2(w, h, acc, false);
#else
  return acc + (float)w[0] * (float)h[0] + (float)w[1] * (float)h[1];
#endif
}

__device__ __forceinline__ h2_t bc_h2(unsigned int v) {
  union { unsigned int u; h2_t h; } cvt;
  cvt.u = v;
  return cvt.h;
}

// K1: scatter-mean wordpieces -> words (bf16). One block per (b, word).
__global__ __launch_bounds__(256) void k_words(const float* __restrict__ emb,
                                               const int* __restrict__ mask,
                                               __hip_bfloat16* __restrict__ words) {
  const int b = blockIdx.x >> 8;
  const int w = blockIdx.x & 255;
  const int tid = threadIdx.x;
  __shared__ int m[SWP];
  m[tid] = mask[b * SWP + tid];
  m[tid + 256] = mask[b * SWP + 256 + tid];
  __syncthreads();
  int lo = 0, hi = SWP;
  while (lo < hi) { int mid = (lo + hi) >> 1; if (m[mid] < w) lo = mid + 1; else hi = mid; }
  int lo2 = lo, hi2 = SWP;
  while (lo2 < hi2) { int mid = (lo2 + hi2) >> 1; if (m[mid] < w + 1) lo2 = mid + 1; else hi2 = mid; }
  const int cnt = lo2 - lo;
  const float inv = (cnt > 0) ? 1.f / (float)cnt : 0.f;
  float s0 = 0.f, s1 = 0.f, s2 = 0.f;
  for (int s = lo; s < lo2; ++s) {
    const float* row = emb + ((size_t)b * SWP + s) * D_;
    s0 += row[tid]; s1 += row[tid + 256]; s2 += row[tid + 512];
  }
  __hip_bfloat16* o = words + ((size_t)b * W_ + w) * D_;
  o[tid]       = __float2bfloat16(s0 * inv);
  o[tid + 256] = __float2bfloat16(s1 * inv);
  o[tid + 512] = __float2bfloat16(s2 * inv);
}

// K2a: concat+convert input weights to bf16 [2048][768]; fused bias b_ih+b_hh [2048]
__global__ __launch_bounds__(256) void k_prep_wih(const float* __restrict__ wf, const float* __restrict__ wr,
                                                  const float* __restrict__ bihf, const float* __restrict__ bhhf,
                                                  const float* __restrict__ bihr, const float* __restrict__ bhhr,
                                                  __hip_bfloat16* __restrict__ wih, float* __restrict__ bias) {
  const int i = blockIdx.x * 256 + threadIdx.x;
  const int n = i / D_;
  const int k = i - n * D_;
  const float v = (n < G4) ? wf[n * D_ + k] : wr[(n - G4) * D_ + k];
  wih[i] = __float2bfloat16(v);
  if (i < N2) {
    bias[i] = (i < G4) ? (bihf[i] + bhhf[i]) : (bihr[i - G4] + bhhr[i - G4]);
  }
}

// K2b: repack w_hh as half2 [dir][128 kk][1024 r]: whhP[d][kk][r] = (w[r][2kk], w[r][2kk+1])
__global__ __launch_bounds__(256) void k_prep_whh(const float* __restrict__ whf,
                                                  const float* __restrict__ whr,
                                                  h2_t* __restrict__ whhP) {
  const int i = blockIdx.x * 256 + threadIdx.x;   // 2*128*1024
  const int d = i >> 17;
  const int kk = (i >> 10) & 127;
  const int r = i & 1023;
  const float* w = d ? whr : whf;
  h2_t v;
  v[0] = (_Float16)w[r * H_ + 2 * kk];
  v[1] = (_Float16)w[r * H_ + 2 * kk + 1];
  whhP[i] = v;
}

// K3: xg = words @ W_ih^T + (b_ih + b_hh), bf16 MFMA, 128x128 tile, out f16
__global__ __launch_bounds__(256) void k_gemm_xg(const __hip_bfloat16* __restrict__ A,
                                                 const __hip_bfloat16* __restrict__ Wt,
                                                 const float* __restrict__ bias,
                                                 _Float16* __restrict__ C) {
  const int bm = blockIdx.y * 128;
  const int bn = blockIdx.x * 128;
  __shared__ __hip_bfloat16 As[128 * 32];
  __shared__ __hip_bfloat16 Bs[128 * 32];
  const int tid = threadIdx.x;
  const int lane = tid & 63;
  const int wave = tid >> 6;
  const int wm = (wave >> 1) * 64;
  const int wn = (wave & 1) * 64;
  const int l15 = lane & 15;
  const int l4 = lane >> 4;
  const int row_a = tid >> 2;
  const int chunk = tid & 3;
  f32x4 acc[4][4] = {};
  for (int k0 = 0; k0 < D_; k0 += 32) {
    const __hip_bfloat16* ga  = A  + (size_t)(bm + row_a) * D_ + k0 + chunk * 8;
    const __hip_bfloat16* ga2 = A  + (size_t)(bm + 64 + row_a) * D_ + k0 + chunk * 8;
    const __hip_bfloat16* gb  = Wt + (size_t)(bn + row_a) * D_ + k0 + chunk * 8;
    const __hip_bfloat16* gb2 = Wt + (size_t)(bn + 64 + row_a) * D_ + k0 + chunk * 8;
    gload_lds16(ga,  As + tid * 8);
    gload_lds16(ga2, As + 2048 + tid * 8);
    gload_lds16(gb,  Bs + tid * 8);
    gload_lds16(gb2, Bs + 2048 + tid * 8);
    __syncthreads();
    bf16x8 af[4], bf[4];
#pragma unroll
    for (int i = 0; i < 4; ++i) {
      af[i] = *(const bf16x8*)(As + (wm + i * 16 + l15) * 32 + l4 * 8);
      bf[i] = *(const bf16x8*)(Bs + (wn + i * 16 + l15) * 32 + l4 * 8);
    }
#pragma unroll
    for (int i = 0; i < 4; ++i)
#pragma unroll
      for (int j = 0; j < 4; ++j)
        acc[i][j] = __builtin_amdgcn_mfma_f32_16x16x32_bf16(af[i], bf[j], acc[i][j], 0, 0, 0);
    __syncthreads();
  }
#pragma unroll
  for (int i = 0; i < 4; ++i) {
    const int m = bm + wm + i * 16 + l4 * 4;
#pragma unroll
    for (int j = 0; j < 4; ++j) {
      const int n = bn + wn + j * 16 + l15;
      const float bs = bias[n];
#pragma unroll
      for (int r = 0; r < 4; ++r)
        C[(size_t)(m + r) * N2 + n] = (_Float16)(acc[i][j][r] + bs);
    }
  }
}

// K4 (R7 best): R3 structure + asm-pinned register weights.
// Block = (dir, batch), 512 threads, 8 waves = 2/SIMD.
// Thread t owns gate rows r1 = low?u:256+u, r2 = r1+512.
// Weights: k-pairs 0..99 per row pinned in VGPRs (200 regs; compiler spills
// to scratch, whose reload stream is L1-port-bound ~3200cyc/step — measured
// floor for this byte count), k-pairs 100..127 in LDS (114.7 KB).
__global__ __launch_bounds__(512)
__attribute__((amdgpu_waves_per_eu(2, 2)))
void k_lstm(const _Float16* __restrict__ xg,   // [M_][2048]
            const h2_t* __restrict__ whhP,     // [2][128][1024]
            float* __restrict__ out) {         // [B_][W_][512]
  const int bx = blockIdx.x;
  const int d = bx & 1;
  const int b = bx >> 1;
  const int t = threadIdx.x;
  const int u = t & 255;
  const bool low = (t < 256);
  const int r1 = low ? u : (256 + u);
  const int r2 = r1 + 512;

  __shared__ __align__(16) _Float16 hbuf[256];        // 128 h2
  __shared__ __align__(16) h2_t wlds[NCH][512][4];    // 114.7 KB
  __shared__ float fo[256][2];

  const h2_t* wp = whhP + (size_t)d * (128 * 1024);

  // Load + PIN register-resident weights (bit patterns in unsigned).
  unsigned wr1[KR2], wr2[KR2];
#pragma unroll
  for (int kk = 0; kk < KR2; ++kk) {
    wr1[kk] = *(const unsigned*)&wp[kk * 1024 + r1];
    wr2[kk] = *(const unsigned*)&wp[kk * 1024 + r2];
  }
#pragma unroll
  for (int kk = 0; kk < KR2; ++kk) {
    asm volatile("" : "+v"(wr1[kk]));
    asm volatile("" : "+v"(wr2[kk]));
  }

  // Stage LDS weight tail: pairs 100..127. chunk c<7 -> row r1, c>=7 -> row r2.
#pragma unroll
  for (int c = 0; c < NCH; ++c) {
    const int row = (c < 7) ? r1 : r2;
    const int kb = KR2 + (c % 7) * 4;
    f32x4 v;
#pragma unroll
    for (int q = 0; q < 4; ++q)
      ((h2_t*)&v)[q] = wp[(kb + q) * 1024 + row];
    *(f32x4*)&wlds[c][t][0] = v;
  }
  if (t < 256) hbuf[t] = (_Float16)0.f;
  __syncthreads();

  float c_state = 0.f;
#pragma unroll 1
  for (int step = 0; step < W_; ++step) {
    const int tt = d ? (W_ - 1 - step) : step;
    const _Float16* xrow = xg + ((size_t)b * W_ + tt) * N2 + d * G4;
    const float xv1 = (float)xrow[r1];
    const float xv2 = (float)xrow[r2];
    float a1a = 0.f, a1b = 0.f, a2a = 0.f, a2b = 0.f;
    if (step > 0) {
      const f32x4* hb4 = (const f32x4*)&hbuf[0];   // 32 chunks of 4 h2
      // pairs 0..99: pinned register weights (25 chunks)
#pragma unroll
      for (int c = 0; c < 25; ++c) {
        const f32x4 hv = hb4[c];
        const h2_t* hp = (const h2_t*)&hv;
        a1a = dot2acc(bc_h2(wr1[c * 4 + 0]), hp[0], a1a);
        a1b = dot2acc(bc_h2(wr1[c * 4 + 1]), hp[1], a1b);
        a2a = dot2acc(bc_h2(wr2[c * 4 + 0]), hp[0], a2a);
        a2b = dot2acc(bc_h2(wr2[c * 4 + 1]), hp[1], a2b);
        a1a = dot2acc(bc_h2(wr1[c * 4 + 2]), hp[2], a1a);
        a1b = dot2acc(bc_h2(wr1[c * 4 + 3]), hp[3], a1b);
        a2a = dot2acc(bc_h2(wr2[c * 4 + 2]), hp[2], a2a);
        a2b = dot2acc(bc_h2(wr2[c * 4 + 3]), hp[3], a2b);
      }
      // pairs 100..127: LDS tail (7 chunks per row)
#pragma unroll
      for (int j = 0; j < 7; ++j) {
        const f32x4 hv = hb4[25 + j];
        const f32x4 w1v = *(const f32x4*)&wlds[j][t][0];
        const f32x4 w2v = *(const f32x4*)&wlds[7 + j][t][0];
        const h2_t* hp = (const h2_t*)&hv;
        const h2_t* w1p = (const h2_t*)&w1v;
        const h2_t* w2p = (const h2_t*)&w2v;
        a1a = dot2acc(w1p[0], hp[0], a1a);
        a1b = dot2acc(w1p[1], hp[1], a1b);
        a2a = dot2acc(w2p[0], hp[0], a2a);
        a2b = dot2acc(w2p[1], hp[1], a2b);
        a1a = dot2acc(w1p[2], hp[2], a1a);
        a1b = dot2acc(w1p[3], hp[3], a1b);
        a2a = dot2acc(w2p[2], hp[2], a2a);
        a2b = dot2acc(w2p[3], hp[3], a2b);
      }
    }
    const float a1 = a1a + a1b + xv1;
    const float a2 = a2a + a2b + xv2;
    if (!low) { fo[u][0] = a1; fo[u][1] = a2; }
    __syncthreads();
    if (low) {
      const float ig = sigm(a1);
      const float gg = tanh_(a2);
      const float fg = sigm(fo[u][0]);
      const float og = sigm(fo[u][1]);
      c_state = fg * c_state + ig * gg;
      const float h = og * tanh_(c_state);
      out[((size_t)b * W_ + tt) * 512 + d * 256 + u] = h;
      hbuf[u] = (_Float16)h;
    }
    __syncthreads();
  }
}

// K5: sent-mean + aspect gather-mean + fc1(relu) + fc2. One block per batch.
__global__ __launch_bounds__(256) void k_head(const float* __restrict__ out,
                                              const int* __restrict__ aidx,
                                              const float* __restrict__ fc1w,
                                              const float* __restrict__ fc1b,
                                              const float* __restrict__ fc2w,
                                              const float* __restrict__ fc2b,
                                              float* __restrict__ logits) {
  const int b = blockIdx.x;
  const int t = threadIdx.x;
  __shared__ float emb[A_][1024];
  __shared__ float h1[A_][256];
  __shared__ float sent[512];
  const float* ob = out + (size_t)b * W_ * 512;
  float s0 = 0.f, s1 = 0.f;
  for (int tt = 0; tt < W_; ++tt) {
    s0 += ob[tt * 512 + t];
    s1 += ob[tt * 512 + 256 + t];
  }
  sent[t] = s0 * (1.f / 256.f);
  sent[t + 256] = s1 * (1.f / 256.f);
  __syncthreads();
  for (int a = 0; a < A_; ++a) {
    int nv = 0;
    float m0 = 0.f, m1 = 0.f;
    for (int k = 0; k < KK_; ++k) {
      const int idx = aidx[(b * A_ + a) * KK_ + k];
      if (idx >= 0) {
        const int tt = min(idx, W_ - 2) + 1;
        m0 += ob[tt * 512 + t];
        m1 += ob[tt * 512 + 256 + t];
        nv++;
      }
    }
    const float inv = nv > 0 ? 1.f / (float)nv : 0.f;
    const bool valid = nv > 0;
    emb[a][t]        = valid ? sent[t] : 0.f;
    emb[a][t + 256]  = valid ? sent[t + 256] : 0.f;
    emb[a][512 + t]       = m0 * inv;
    emb[a][512 + 256 + t] = m1 * inv;
  }
  __syncthreads();
  {
    float acc[A_];
#pragma unroll
    for (int a = 0; a < A_; ++a) acc[a] = fc1b[t];
    const float* wrow = fc1w + (size_t)t * 1024;
    for (int j = 0; j < 1024; j += 4) {
      const float4 w = *(const float4*)(wrow + j);
#pragma unroll
      for (int a = 0; a < A_; ++a) {
        const float4 e = *(const float4*)(&emb[a][j]);
        acc[a] += w.x * e.x + w.y * e.y + w.z * e.z + w.w * e.w;
      }
    }
#pragma unroll
    for (int a = 0; a < A_; ++a) h1[a][t] = fmaxf(acc[a], 0.f);
  }
  __syncthreads();
  if (t < A_ * 4) {
    const int a = t >> 2, l = t & 3;
    float acc = fc2b[l];
    const float* w = fc2w + l * 256;
    for (int j = 0; j < 256; ++j) acc += w[j] * h1[a][j];
    logits[(b * A_ + a) * 4 + l] = acc;
  }
}

extern "C" void kernel_launch(void* const* d_in, const int* in_sizes, int n_in,
                              void* d_out, int out_size, void* d_ws, size_t ws_size,
                              hipStream_t stream) {
  const float* emb  = (const float*)d_in[0];
  const int*   mask = (const int*)d_in[1];
  const int*   aidx = (const int*)d_in[2];
  const float* wihf = (const float*)d_in[3];
  const float* whhf = (const float*)d_in[4];
  const float* bihf = (const float*)d_in[5];
  const float* bhhf = (const float*)d_in[6];
  const float* wihr = (const float*)d_in[7];
  const float* whhr = (const float*)d_in[8];
  const float* bihr = (const float*)d_in[9];
  const float* bhhr = (const float*)d_in[10];
  const float* fc1w = (const float*)d_in[11];
  const float* fc1b = (const float*)d_in[12];
  const float* fc2w = (const float*)d_in[13];
  const float* fc2b = (const float*)d_in[14];
  float* logits = (float*)d_out;

  char* ws = (char*)d_ws;
  size_t off = 0;
  auto alloc = [&](size_t bytes) -> void* {
    void* p = ws + off;
    off += (bytes + 255) & ~(size_t)255;
    return p;
  };
  __hip_bfloat16* words = (__hip_bfloat16*)alloc((size_t)M_ * D_ * 2);
  _Float16*       xg    = (_Float16*)alloc((size_t)M_ * N2 * 2);
  __hip_bfloat16* wih   = (__hip_bfloat16*)alloc((size_t)N2 * D_ * 2);
  float*          bias  = (float*)alloc((size_t)N2 * 4);
  h2_t*           whhP  = (h2_t*)alloc((size_t)2 * 128 * 1024 * 4);
  float*          outh  = (float*)alloc((size_t)B_ * W_ * 512 * 4);

  k_words<<<B_ * W_, 256, 0, stream>>>(emb, mask, words);
  k_prep_wih<<<(N2 * D_) / 256, 256, 0, stream>>>(wihf, wihr, bihf, bhhf, bihr, bhhr, wih, bias);
  k_prep_whh<<<(2 * 128 * 1024) / 256, 256, 0, stream>>>(whhf, whhr, whhP);
  dim3 gg(N2 / 128, M_ / 128);
  k_gemm_xg<<<gg, 256, 0, stream>>>(words, wih, bias, xg);
  k_lstm<<<B_ * 2, 512, 0, stream>>>(xg, whhP, outh);
  k_head<<<B_, 256, 0, stream>>>(outh, aidx, fc1w, fc1b, fc2w, fc2b, logits);
}